// Round 16
// baseline (488.873 us; speedup 1.0000x reference)
//
#include <hip/hip_runtime.h>
#include <hip/hip_bf16.h>

#define NN 100000
#define NE 1600000
#define D  128
#define BN_EPS 1e-5f

// counting-sort geometry (dst path)
#define CB  782                 // coarse bins = ceil(NN/128), bin = 128 nodes
#define NC  256                 // chunks
#define EPC (NE / NC)           // 6250 edges per chunk
// slice-histogram geometry (src path): packed 4x 8-bit counters per int
#define NSLICE  2
#define SLICESZ 61600           // nodes per slice; 2*61600 >= NN
#define SW      (SLICESZ / 4)   // 15400 words = 61.6 KB LDS
#define SCH     256             // chunks -> NSLICE*SCH = 512 blocks
#define EPH (NE / SCH)          // 6250 (== EPC, chunk-aligned with dst path)

#define GB   ((NN + 63) / 64)            // gemm blocks = 1563
#define SMB  ((NSLICE * SW + 255) / 256) // smerge blocks = 121

typedef __attribute__((ext_vector_type(8))) short bf16x8;
typedef __attribute__((ext_vector_type(4))) float f32x4;

#define WLD 136   // padded row stride (ushorts) for W^T in LDS: 2-way banks only

static __device__ __forceinline__ ushort f2bf(float f) {
    __hip_bfloat16 b = __float2bfloat16(f);
    return *reinterpret_cast<ushort*>(&b);
}
static __device__ __forceinline__ float bflo(unsigned v) {
    return __uint_as_float((v & 0xffffu) << 16);
}
static __device__ __forceinline__ float bfhi(unsigned v) {
    return __uint_as_float(v & 0xffff0000u);
}

// ---------------- Kernel 1 (fused front-end, 512 blocks) ----------------
__global__ __launch_bounds__(256) void k_front(const int* __restrict__ src,
                                               const int* __restrict__ dst,
                                               const float* __restrict__ W,
                                               ushort* __restrict__ WT,
                                               int* __restrict__ SP,
                                               int* __restrict__ P,
                                               float* __restrict__ stats) {
    __shared__ int hist[SW];   // 61.6 KB
    __shared__ int dh[CB];     // 3.1 KB
    const int t = threadIdx.x;
    const int s = blockIdx.x >> 8;
    const int c = blockIdx.x & 255;
    for (int i = t; i < SW; i += 256) hist[i] = 0;
    for (int i = t; i < CB; i += 256) dh[i] = 0;
    __syncthreads();

    const int lo = s * SLICESZ;
    const int base = c * EPH;
    for (int i = t; i < EPH; i += 256) {
        int k = src[base + i] - lo;
        if ((unsigned)k < (unsigned)SLICESZ)
            atomicAdd(&hist[k >> 2], 1 << ((k & 3) * 8));
    }
    if (s == 0) {
        for (int i = t; i < EPH; i += 256)     // EPH == EPC, same chunk base
            atomicAdd(&dh[dst[base + i] >> 7], 1);
    }
    __syncthreads();

    int* outS = SP + (size_t)blockIdx.x * SW;
    for (int i = t; i < SW; i += 256) outS[i] = hist[i];
    if (s == 0)
        for (int i = t; i < CB; i += 256) P[i * NC + c] = dh[i];
    if (s == 1 && c < 64) {                    // W^T cast: 64 blocks x 256 elems
        int i = c * 256 + t;
        int n = i >> 7, k2 = i & 127;
        WT[i] = f2bf(W[k2 * D + n]);
    }
    if (s == 1 && c == 64) stats[t] = 0.0f;    // 256 floats
}

// ---------------- Kernel 2 (fused): cscanA (782 blocks) || smerge (121 blocks) ----------------
__global__ __launch_bounds__(256) void k_mid(int* __restrict__ P,
                                             int* __restrict__ bintotal,
                                             const int* __restrict__ SP,
                                             float* __restrict__ degout) {
    const int t = threadIdx.x;
    if (blockIdx.x < CB) {
        __shared__ int sh[NC];
        const int b = blockIdx.x;
        const int v = P[b * NC + t];
        sh[t] = v;
        __syncthreads();
        for (int off = 1; off < NC; off <<= 1) {
            int u = (t >= off) ? sh[t - off] : 0;
            __syncthreads();
            sh[t] += u;
            __syncthreads();
        }
        P[b * NC + t] = sh[t] - v;
        if (t == NC - 1) bintotal[b] = sh[t];
    } else {
        int w = (blockIdx.x - CB) * 256 + t;
        if (w >= NSLICE * SW) return;
        const int s = w / SW, wi = w - s * SW;
        const int n0 = s * SLICESZ + wi * 4;
        if (n0 >= NN) return;
        const int* col = SP + (size_t)s * SCH * SW + wi;
        int b0 = 0, b1 = 0, b2 = 0, b3 = 0;
#pragma unroll 8
        for (int c = 0; c < SCH; ++c) {
            unsigned v = (unsigned)col[(size_t)c * SW];
            b0 += v & 0xFF;
            b1 += (v >> 8) & 0xFF;
            b2 += (v >> 16) & 0xFF;
            b3 += (v >> 24);
        }
        degout[n0] = (float)b0;
        if (n0 + 1 < NN) degout[n0 + 1] = (float)b1;
        if (n0 + 2 < NN) degout[n0 + 2] = (float)b2;
        if (n0 + 3 < NN) degout[n0 + 3] = (float)b3;
    }
}

// ---------------- Kernel 3 (fused): gemm (1563 blocks) || cscatter+binbase (256 blocks) ----------
__global__ __launch_bounds__(256) void k_csg(const float* __restrict__ x,
                                             const float* __restrict__ degout,
                                             const ushort* __restrict__ WT,
                                             ushort* __restrict__ h,
                                             const int* __restrict__ dst,
                                             const int* __restrict__ src,
                                             const int* __restrict__ P,
                                             const int* __restrict__ bintotal,
                                             int* __restrict__ binbase,
                                             int* __restrict__ sedge) {
    __shared__ ushort Wl[D * WLD];   // 34.8 KB (gemm branch)
    __shared__ int part[256];        // 1 KB  (scan partials)
    __shared__ int bb[CB];           // 3.1 KB (exclusive binbase)
    __shared__ int cur[CB];          // 3.1 KB (scatter cursors)
    const int t = threadIdx.x;

    if (blockIdx.x < GB) {
        // ===== GEMM: h = (x * rsqrt(max(deg_out,1))) @ W via MFMA =====
        for (int s = t; s < 2048; s += 256) {
            int row = s >> 4, slot = s & 15;
            uint4 v = *reinterpret_cast<const uint4*>(WT + row * D + slot * 8);
            *reinterpret_cast<uint4*>(&Wl[row * WLD + slot * 8]) = v;
        }
        __syncthreads();

        const int wave = t >> 6;
        const int lane = t & 63;
        const int m16  = lane & 15;
        const int kq   = lane >> 4;
        const int row  = blockIdx.x * 64 + wave * 16 + m16;
        const int rc   = row < NN ? row : NN - 1;

        const float nrm = rsqrtf(fmaxf(degout[rc], 1.0f));

        bf16x8 afrag[4];
        const float* xr = x + (size_t)rc * D + kq * 8;
#pragma unroll
        for (int kt = 0; kt < 4; ++kt) {
            f32x4 lo = *reinterpret_cast<const f32x4*>(xr + kt * 32);
            f32x4 hi = *reinterpret_cast<const f32x4*>(xr + kt * 32 + 4);
            union { bf16x8 v; ushort u[8]; } af;
#pragma unroll
            for (int j = 0; j < 4; ++j) {
                af.u[j]     = f2bf(lo[j] * nrm);
                af.u[4 + j] = f2bf(hi[j] * nrm);
            }
            afrag[kt] = af.v;
        }

        f32x4 acc[8];
#pragma unroll
        for (int nt = 0; nt < 8; ++nt) acc[nt] = (f32x4)(0.0f);

#pragma unroll
        for (int kt = 0; kt < 4; ++kt) {
#pragma unroll
            for (int nt = 0; nt < 8; ++nt) {
                int n = nt * 16 + m16;
                const bf16x8 bfrag = *reinterpret_cast<const bf16x8*>(
                    &Wl[n * WLD + kt * 32 + kq * 8]);
                acc[nt] = __builtin_amdgcn_mfma_f32_16x16x32_bf16(afrag[kt], bfrag, acc[nt], 0, 0, 0);
            }
        }

        const int orow = blockIdx.x * 64 + wave * 16 + kq * 4;
#pragma unroll
        for (int nt = 0; nt < 8; ++nt) {
#pragma unroll
            for (int r = 0; r < 4; ++r) {
                int rr = orow + r;
                if (rr < NN) h[(size_t)rr * D + nt * 16 + m16] = f2bf(acc[nt][r]);
            }
        }
    } else {
        // ===== CSCATTER with in-block binbase scan =====
        const int c = blockIdx.x - GB;
        int val[4];
        int sum = 0;
#pragma unroll
        for (int j = 0; j < 4; ++j) {
            int idx = t * 4 + j;
            val[j] = (idx < CB) ? bintotal[idx] : 0;
            sum += val[j];
        }
        part[t] = sum;
        __syncthreads();
        for (int off = 1; off < 256; off <<= 1) {
            int u = (t >= off) ? part[t - off] : 0;
            __syncthreads();
            part[t] += u;
            __syncthreads();
        }
        int run = (t == 0) ? 0 : part[t - 1];
#pragma unroll
        for (int j = 0; j < 4; ++j) {
            int idx = t * 4 + j;
            if (idx < CB) bb[idx] = run;
            run += val[j];
        }
        __syncthreads();
        if (c == 0) {   // publish binbase for k_fine
            for (int i = t; i < CB; i += 256) binbase[i] = bb[i];
            if (t == 0) binbase[CB] = part[255];   // = NE
        }
        for (int i = t; i < CB; i += 256) cur[i] = bb[i] + P[i * NC + c];
        __syncthreads();
        const int base = c * EPC;
        for (int i = t; i < EPC; i += 256) {
            int d = dst[base + i];
            int pos = atomicAdd(&cur[d >> 7], 1);   // LDS atomic
            sedge[pos] = src[base + i] | ((d & 127) << 17);
        }
    }
}

// ---------------- Kernel 4: per-coarse-bin fine CSR. Emits ptr, esrc. ----------------
__global__ __launch_bounds__(256) void k_fine(const int* __restrict__ sedge,
                                              const int* __restrict__ binbase,
                                              int* __restrict__ ptr,
                                              int* __restrict__ esrc) {
    __shared__ int fh[128], fp[128], fcur[128];
    const int b = blockIdx.x;
    const int t = threadIdx.x;
    const int lo = binbase[b], hi = binbase[b + 1];
    if (t < 128) fh[t] = 0;
    __syncthreads();
    for (int i = lo + t; i < hi; i += 256)
        atomicAdd(&fh[(unsigned)sedge[i] >> 17], 1);
    __syncthreads();
    if (t < 128) fp[t] = fh[t];
    __syncthreads();
    for (int off = 1; off < 128; off <<= 1) {
        int u = (t < 128 && t >= off) ? fp[t - off] : 0;
        __syncthreads();
        if (t < 128) fp[t] += u;
        __syncthreads();
    }
    if (t < 128) {
        const int node = b * 128 + t;
        const int ex = fp[t] - fh[t];
        fcur[t] = ex;
        if (node < NN) {
            ptr[node] = lo + ex;
        } else if (node == NN) {
            ptr[NN] = lo + ex;
        }
    }
    __syncthreads();
    for (int i = lo + t; i < hi; i += 256) {
        unsigned v = (unsigned)sedge[i];
        int pos = atomicAdd(&fcur[v >> 17], 1);   // LDS atomic
        esrc[lo + pos] = v & 0x1FFFF;
    }
}

// ---------------- Kernel 5: XCD-sliced gather-sum ----------------
// Grid = ceil(NN/8) * 8; slice = blockIdx & 7 (16 cols = 32 B of h).
// With round-robin blockIdx%8 -> XCD mapping, each XCD only touches its own
// 3.2 MB column slice of h -> L2-resident. Correct regardless of mapping.
__global__ __launch_bounds__(256) void k_agg(const ushort* __restrict__ h,
                                             const int* __restrict__ ptr,
                                             const int* __restrict__ esrc,
                                             const float* __restrict__ b,
                                             ushort* __restrict__ h2) {
    const int slice = blockIdx.x & 7;
    const int ng    = blockIdx.x >> 3;
    const int wid   = threadIdx.x >> 6;
    const int lane  = threadIdx.x & 63;
    const int eg    = lane >> 1;               // edge slot 0..31
    const int cw    = lane & 1;                // col word 0..1 (uint4 = 8 bf16)
    const int cb    = slice * 16 + cw * 8;     // ushort col offset

#pragma unroll
    for (int rep = 0; rep < 2; ++rep) {
        const int node = ng * 8 + rep * 4 + wid;
        if (node < NN) {
            const int s0 = ptr[node];
            const int s1 = ptr[node + 1];
            float acc[8];
#pragma unroll
            for (int j = 0; j < 8; ++j) acc[j] = 0.0f;
            for (int i = s0 + eg; i < s1; i += 32) {
                int idx = esrc[i];
                uint4 v = *reinterpret_cast<const uint4*>(h + (size_t)idx * D + cb);
                acc[0] += bflo(v.x); acc[1] += bfhi(v.x);
                acc[2] += bflo(v.y); acc[3] += bfhi(v.y);
                acc[4] += bflo(v.z); acc[5] += bfhi(v.z);
                acc[6] += bflo(v.w); acc[7] += bfhi(v.w);
            }
            // fold 32 edge slots: lanes with same cw, eg ^ {1,2,4,8,16}
#pragma unroll
            for (int j = 0; j < 8; ++j) {
                acc[j] += __shfl_xor(acc[j], 2, 64);
                acc[j] += __shfl_xor(acc[j], 4, 64);
                acc[j] += __shfl_xor(acc[j], 8, 64);
                acc[j] += __shfl_xor(acc[j], 16, 64);
                acc[j] += __shfl_xor(acc[j], 32, 64);
            }
            if (eg == 0) {
                const float nrm = rsqrtf(fmaxf((float)(s1 - s0), 1.0f));
                unsigned w[4];
#pragma unroll
                for (int m = 0; m < 4; ++m) {
                    float e0 = acc[2 * m]     * nrm + b[cb + 2 * m];
                    float e1 = acc[2 * m + 1] * nrm + b[cb + 2 * m + 1];
                    w[m] = (unsigned)f2bf(e0) | ((unsigned)f2bf(e1) << 16);
                }
                uint4 o; o.x = w[0]; o.y = w[1]; o.z = w[2]; o.w = w[3];
                *reinterpret_cast<uint4*>(h2 + (size_t)node * D + cb) = o;
            }
        }
    }
}

// ---------------- Kernel 6: column sums / sumsq of bf16 h2 ----------------
__global__ __launch_bounds__(256) void k_stats(const unsigned* __restrict__ h2u,
                                               float* __restrict__ stats) {
    __shared__ float red[4][256];
    const int t = threadIdx.x;
    float s1lo = 0.f, s1hi = 0.f, s2lo = 0.f, s2hi = 0.f;
    const int total = NN * (D / 2);
    const int stride = gridDim.x * 256;
    for (int i = blockIdx.x * 256 + t; i < total; i += stride) {
        unsigned v = h2u[i];
        float lo = bflo(v), hi = bfhi(v);
        s1lo += lo; s1hi += hi;
        s2lo += lo * lo; s2hi += hi * hi;
    }
    red[0][t] = s1lo; red[1][t] = s1hi; red[2][t] = s2lo; red[3][t] = s2hi;
    __syncthreads();
    if (t < 64) {
        const int c = t * 2;
        float a0 = red[0][t] + red[0][t + 64] + red[0][t + 128] + red[0][t + 192];
        float a1 = red[1][t] + red[1][t + 64] + red[1][t + 128] + red[1][t + 192];
        float q0 = red[2][t] + red[2][t + 64] + red[2][t + 128] + red[2][t + 192];
        float q1 = red[3][t] + red[3][t + 64] + red[3][t + 128] + red[3][t + 192];
        atomicAdd(&stats[c], a0);
        atomicAdd(&stats[c + 1], a1);
        atomicAdd(&stats[128 + c], q0);
        atomicAdd(&stats[128 + c + 1], q1);
    }
}

// ---------------- Kernel 7: BN + ReLU + residual, 16B vectorized ----------------
__global__ void k_final(const uint2* __restrict__ h2v, const float4* __restrict__ xv,
                        const float* __restrict__ gamma, const float* __restrict__ beta,
                        const float* __restrict__ stats, float4* __restrict__ outv) {
    const int i = blockIdx.x * 256 + threadIdx.x;
    const int total = NN * (D / 4);
    if (i >= total) return;
    const int c = (i & 31) * 4;
    const float inv_n = 1.0f / (float)NN;
    uint2 v = h2v[i];
    float4 xx = xv[i];
    float hv[4] = { bflo(v.x), bfhi(v.x), bflo(v.y), bfhi(v.y) };
    float xr[4] = { xx.x, xx.y, xx.z, xx.w };
    float o[4];
#pragma unroll
    for (int m = 0; m < 4; ++m) {
        float mean = stats[c + m] * inv_n;
        float var  = stats[128 + c + m] * inv_n - mean * mean;
        float t = (hv[m] - mean) * rsqrtf(var + BN_EPS) * gamma[c + m] + beta[c + m];
        o[m] = fmaxf(t, 0.0f) + xr[m];
    }
    float4 ov; ov.x = o[0]; ov.y = o[1]; ov.z = o[2]; ov.w = o[3];
    outv[i] = ov;
}

extern "C" void kernel_launch(void* const* d_in, const int* in_sizes, int n_in,
                              void* d_out, int out_size, void* d_ws, size_t ws_size,
                              hipStream_t stream) {
    const float* x     = (const float*)d_in[0];
    const int*   src   = (const int*)d_in[1];
    const int*   dst   = (const int*)d_in[2];
    const float* W     = (const float*)d_in[3];
    const float* b     = (const float*)d_in[4];
    const float* gamma = (const float*)d_in[5];
    const float* beta  = (const float*)d_in[6];
    float* out = (float*)d_out;

    // Workspace layout (first NN*D floats reserved for h2/overlays)
    float* ws     = (float*)d_ws;
    ushort* h2    = (ushort*)ws;                      // NN*D bf16 (written by k_agg)
    float* degout = ws + (size_t)NN * D;              // NN
    float* stats  = degout + NN;                      // 256 (zeroed by k_front)
    int*   ptr    = (int*)(stats + 256);              // NN+1
    int*   esrc   = ptr + (NN + 1);                   // NE
    ushort* WT    = (ushort*)(esrc + NE);             // 128*128 bf16

    // Overlays in the h2 region (all dead before k_agg writes h2): ~38.8 MB < 51.2 MB
    int* sedge    = (int*)ws;                         // NE (packed src | (dst&127)<<17)
    int* SP       = sedge + NE;                       // NSLICE*SCH*SW = 31.5 MB
    int* P        = SP + (size_t)NSLICE * SCH * SW;   // CB*NC
    int* bintotal = P + (size_t)CB * NC;              // CB
    int* binbase  = bintotal + CB;                    // CB+1

    // h (bf16) lives in d_out (overwritten by k_final at the end)
    ushort* h = (ushort*)d_out;

    k_front<<<NSLICE * SCH, 256, 0, stream>>>(src, dst, W, WT, SP, P, stats);
    k_mid<<<CB + SMB, 256, 0, stream>>>(P, bintotal, SP, degout);
    k_csg<<<GB + NC, 256, 0, stream>>>(x, degout, WT, h, dst, src, P, bintotal, binbase, sedge);
    k_fine<<<CB, 256, 0, stream>>>(sedge, binbase, ptr, esrc);
    k_agg<<<((NN + 7) / 8) * 8, 256, 0, stream>>>(h, ptr, esrc, b, h2);
    k_stats<<<1024, 256, 0, stream>>>((const unsigned*)h2, stats);
    k_final<<<(NN * (D / 4) + 255) / 256, 256, 0, stream>>>((const uint2*)h2, (const float4*)x,
                                                            gamma, beta, stats, (float4*)out);
}

// Round 17
// 224.813 us; speedup vs baseline: 2.1746x; 2.1746x over previous
//
#include <hip/hip_runtime.h>
#include <hip/hip_bf16.h>

#define NN 100000
#define NE 1600000
#define D  128
#define BN_EPS 1e-5f

// counting-sort geometry (dst path)
#define CB  782                 // coarse bins = ceil(NN/128), bin = 128 nodes
#define NC  256                 // chunks
#define EPC (NE / NC)           // 6250 edges per chunk
// slice-histogram geometry (src path): packed 4x 8-bit counters per int
#define NSLICE  2
#define SLICESZ 61600           // nodes per slice; 2*61600 >= NN
#define SW      (SLICESZ / 4)   // 15400 words = 61.6 KB LDS
#define SCH     256             // chunks -> NSLICE*SCH = 512 blocks
#define EPH (NE / SCH)          // 6250 (== EPC, chunk-aligned with dst path)

#define GB   ((NN + 63) / 64)            // gemm blocks = 1563
#define SMB  ((NSLICE * SW + 255) / 256) // smerge blocks = 121

typedef __attribute__((ext_vector_type(8))) short bf16x8;
typedef __attribute__((ext_vector_type(4))) float f32x4;

#define WLD 136   // padded row stride (ushorts) for W^T in LDS: 2-way banks only

static __device__ __forceinline__ ushort f2bf(float f) {
    __hip_bfloat16 b = __float2bfloat16(f);
    return *reinterpret_cast<ushort*>(&b);
}
static __device__ __forceinline__ float bflo(unsigned v) {
    return __uint_as_float((v & 0xffffu) << 16);
}
static __device__ __forceinline__ float bfhi(unsigned v) {
    return __uint_as_float(v & 0xffff0000u);
}

// ---------------- Kernel 1 (fused front-end, 512 blocks) ----------------
__global__ __launch_bounds__(256) void k_front(const int* __restrict__ src,
                                               const int* __restrict__ dst,
                                               const float* __restrict__ W,
                                               ushort* __restrict__ WT,
                                               int* __restrict__ SP,
                                               int* __restrict__ P,
                                               float* __restrict__ stats) {
    __shared__ int hist[SW];   // 61.6 KB
    __shared__ int dh[CB];     // 3.1 KB
    const int t = threadIdx.x;
    const int s = blockIdx.x >> 8;
    const int c = blockIdx.x & 255;
    for (int i = t; i < SW; i += 256) hist[i] = 0;
    for (int i = t; i < CB; i += 256) dh[i] = 0;
    __syncthreads();

    const int lo = s * SLICESZ;
    const int base = c * EPH;
    for (int i = t; i < EPH; i += 256) {
        int k = src[base + i] - lo;
        if ((unsigned)k < (unsigned)SLICESZ)
            atomicAdd(&hist[k >> 2], 1 << ((k & 3) * 8));
    }
    if (s == 0) {
        for (int i = t; i < EPH; i += 256)     // EPH == EPC, same chunk base
            atomicAdd(&dh[dst[base + i] >> 7], 1);
    }
    __syncthreads();

    int* outS = SP + (size_t)blockIdx.x * SW;
    for (int i = t; i < SW; i += 256) outS[i] = hist[i];
    if (s == 0)
        for (int i = t; i < CB; i += 256) P[i * NC + c] = dh[i];
    if (s == 1 && c < 64) {                    // W^T cast: 64 blocks x 256 elems
        int i = c * 256 + t;
        int n = i >> 7, k2 = i & 127;
        WT[i] = f2bf(W[k2 * D + n]);
    }
    if (s == 1 && c == 64) stats[t] = 0.0f;    // 256 floats
}

// ---------------- Kernel 2 (fused): cscanA (782 blocks) || smerge (121 blocks) ----------------
__global__ __launch_bounds__(256) void k_mid(int* __restrict__ P,
                                             int* __restrict__ bintotal,
                                             const int* __restrict__ SP,
                                             float* __restrict__ degout) {
    const int t = threadIdx.x;
    if (blockIdx.x < CB) {
        __shared__ int sh[NC];
        const int b = blockIdx.x;
        const int v = P[b * NC + t];
        sh[t] = v;
        __syncthreads();
        for (int off = 1; off < NC; off <<= 1) {
            int u = (t >= off) ? sh[t - off] : 0;
            __syncthreads();
            sh[t] += u;
            __syncthreads();
        }
        P[b * NC + t] = sh[t] - v;
        if (t == NC - 1) bintotal[b] = sh[t];
    } else {
        int w = (blockIdx.x - CB) * 256 + t;
        if (w >= NSLICE * SW) return;
        const int s = w / SW, wi = w - s * SW;
        const int n0 = s * SLICESZ + wi * 4;
        if (n0 >= NN) return;
        const int* col = SP + (size_t)s * SCH * SW + wi;
        int b0 = 0, b1 = 0, b2 = 0, b3 = 0;
#pragma unroll 8
        for (int c = 0; c < SCH; ++c) {
            unsigned v = (unsigned)col[(size_t)c * SW];
            b0 += v & 0xFF;
            b1 += (v >> 8) & 0xFF;
            b2 += (v >> 16) & 0xFF;
            b3 += (v >> 24);
        }
        degout[n0] = (float)b0;
        if (n0 + 1 < NN) degout[n0 + 1] = (float)b1;
        if (n0 + 2 < NN) degout[n0 + 2] = (float)b2;
        if (n0 + 3 < NN) degout[n0 + 3] = (float)b3;
    }
}

// ---------------- Kernel 3 (fused): gemm (1563 blocks) || cscatter+binbase (256 blocks) ----------
__global__ __launch_bounds__(256) void k_csg(const float* __restrict__ x,
                                             const float* __restrict__ degout,
                                             const ushort* __restrict__ WT,
                                             ushort* __restrict__ h,
                                             const int* __restrict__ dst,
                                             const int* __restrict__ src,
                                             const int* __restrict__ P,
                                             const int* __restrict__ bintotal,
                                             int* __restrict__ binbase,
                                             int* __restrict__ sedge) {
    __shared__ ushort Wl[D * WLD];   // 34.8 KB (gemm branch)
    __shared__ int part[256];        // 1 KB  (scan partials)
    __shared__ int bb[CB];           // 3.1 KB (exclusive binbase)
    __shared__ int cur[CB];          // 3.1 KB (scatter cursors)
    const int t = threadIdx.x;

    if (blockIdx.x < GB) {
        // ===== GEMM: h = (x * rsqrt(max(deg_out,1))) @ W via MFMA =====
        for (int s = t; s < 2048; s += 256) {
            int row = s >> 4, slot = s & 15;
            uint4 v = *reinterpret_cast<const uint4*>(WT + row * D + slot * 8);
            *reinterpret_cast<uint4*>(&Wl[row * WLD + slot * 8]) = v;
        }
        __syncthreads();

        const int wave = t >> 6;
        const int lane = t & 63;
        const int m16  = lane & 15;
        const int kq   = lane >> 4;
        const int row  = blockIdx.x * 64 + wave * 16 + m16;
        const int rc   = row < NN ? row : NN - 1;

        const float nrm = rsqrtf(fmaxf(degout[rc], 1.0f));

        bf16x8 afrag[4];
        const float* xr = x + (size_t)rc * D + kq * 8;
#pragma unroll
        for (int kt = 0; kt < 4; ++kt) {
            f32x4 lo = *reinterpret_cast<const f32x4*>(xr + kt * 32);
            f32x4 hi = *reinterpret_cast<const f32x4*>(xr + kt * 32 + 4);
            union { bf16x8 v; ushort u[8]; } af;
#pragma unroll
            for (int j = 0; j < 4; ++j) {
                af.u[j]     = f2bf(lo[j] * nrm);
                af.u[4 + j] = f2bf(hi[j] * nrm);
            }
            afrag[kt] = af.v;
        }

        f32x4 acc[8];
#pragma unroll
        for (int nt = 0; nt < 8; ++nt) acc[nt] = (f32x4)(0.0f);

#pragma unroll
        for (int kt = 0; kt < 4; ++kt) {
#pragma unroll
            for (int nt = 0; nt < 8; ++nt) {
                int n = nt * 16 + m16;
                const bf16x8 bfrag = *reinterpret_cast<const bf16x8*>(
                    &Wl[n * WLD + kt * 32 + kq * 8]);
                acc[nt] = __builtin_amdgcn_mfma_f32_16x16x32_bf16(afrag[kt], bfrag, acc[nt], 0, 0, 0);
            }
        }

        const int orow = blockIdx.x * 64 + wave * 16 + kq * 4;
#pragma unroll
        for (int nt = 0; nt < 8; ++nt) {
#pragma unroll
            for (int r = 0; r < 4; ++r) {
                int rr = orow + r;
                if (rr < NN) h[(size_t)rr * D + nt * 16 + m16] = f2bf(acc[nt][r]);
            }
        }
    } else {
        // ===== CSCATTER with in-block binbase scan =====
        const int c = blockIdx.x - GB;
        int val[4];
        int sum = 0;
#pragma unroll
        for (int j = 0; j < 4; ++j) {
            int idx = t * 4 + j;
            val[j] = (idx < CB) ? bintotal[idx] : 0;
            sum += val[j];
        }
        part[t] = sum;
        __syncthreads();
        for (int off = 1; off < 256; off <<= 1) {
            int u = (t >= off) ? part[t - off] : 0;
            __syncthreads();
            part[t] += u;
            __syncthreads();
        }
        int run = (t == 0) ? 0 : part[t - 1];
#pragma unroll
        for (int j = 0; j < 4; ++j) {
            int idx = t * 4 + j;
            if (idx < CB) bb[idx] = run;
            run += val[j];
        }
        __syncthreads();
        if (c == 0) {   // publish binbase for k_fine
            for (int i = t; i < CB; i += 256) binbase[i] = bb[i];
            if (t == 0) binbase[CB] = part[255];   // = NE
        }
        for (int i = t; i < CB; i += 256) cur[i] = bb[i] + P[i * NC + c];
        __syncthreads();
        const int base = c * EPC;
        for (int i = t; i < EPC; i += 256) {
            int d = dst[base + i];
            int pos = atomicAdd(&cur[d >> 7], 1);   // LDS atomic
            sedge[pos] = src[base + i] | ((d & 127) << 17);
        }
    }
}

// ---------------- Kernel 4: per-coarse-bin fine CSR. Emits ptr, esrc. ----------------
__global__ __launch_bounds__(256) void k_fine(const int* __restrict__ sedge,
                                              const int* __restrict__ binbase,
                                              int* __restrict__ ptr,
                                              int* __restrict__ esrc) {
    __shared__ int fh[128], fp[128], fcur[128];
    const int b = blockIdx.x;
    const int t = threadIdx.x;
    const int lo = binbase[b], hi = binbase[b + 1];
    if (t < 128) fh[t] = 0;
    __syncthreads();
    for (int i = lo + t; i < hi; i += 256)
        atomicAdd(&fh[(unsigned)sedge[i] >> 17], 1);
    __syncthreads();
    if (t < 128) fp[t] = fh[t];
    __syncthreads();
    for (int off = 1; off < 128; off <<= 1) {
        int u = (t < 128 && t >= off) ? fp[t - off] : 0;
        __syncthreads();
        if (t < 128) fp[t] += u;
        __syncthreads();
    }
    if (t < 128) {
        const int node = b * 128 + t;
        const int ex = fp[t] - fh[t];
        fcur[t] = ex;
        if (node < NN) {
            ptr[node] = lo + ex;
        } else if (node == NN) {
            ptr[NN] = lo + ex;
        }
    }
    __syncthreads();
    for (int i = lo + t; i < hi; i += 256) {
        unsigned v = (unsigned)sedge[i];
        int pos = atomicAdd(&fcur[v >> 17], 1);   // LDS atomic
        esrc[lo + pos] = v & 0x1FFFF;
    }
}

// ---------------- Kernel 5: gather-sum, 16 lanes/edge x 16B, 16 edges in flight ----------------
__global__ __launch_bounds__(256) void k_agg(const ushort* __restrict__ h,
                                             const int* __restrict__ ptr,
                                             const int* __restrict__ esrc,
                                             const float* __restrict__ b,
                                             ushort* __restrict__ h2) {
    const int node = blockIdx.x * 4 + (threadIdx.x >> 6);
    const int lane = threadIdx.x & 63;
    if (node >= NN) return;
    const int s0 = ptr[node];
    const int s1 = ptr[node + 1];
    const int eg = lane >> 4;          // edge slot 0..3
    const int cb = (lane & 15) * 8;    // column block: 8 bf16 = 16 B

    float acc[8];
#pragma unroll
    for (int j = 0; j < 8; ++j) acc[j] = 0.0f;

    for (int i = s0; i < s1; i += 16) {
        int  idx[4];
        bool p[4];
        uint4 v[4];
#pragma unroll
        for (int u = 0; u < 4; ++u) {
            int ii = i + eg + 4 * u;
            p[u] = ii < s1;
            if (p[u]) idx[u] = esrc[ii];
        }
#pragma unroll
        for (int u = 0; u < 4; ++u)
            if (p[u]) v[u] = *reinterpret_cast<const uint4*>(h + (size_t)idx[u] * D + cb);
#pragma unroll
        for (int u = 0; u < 4; ++u) {
            if (p[u]) {
                acc[0] += bflo(v[u].x); acc[1] += bfhi(v[u].x);
                acc[2] += bflo(v[u].y); acc[3] += bfhi(v[u].y);
                acc[4] += bflo(v[u].z); acc[5] += bfhi(v[u].z);
                acc[6] += bflo(v[u].w); acc[7] += bfhi(v[u].w);
            }
        }
    }
#pragma unroll
    for (int j = 0; j < 8; ++j) {
        acc[j] += __shfl_xor(acc[j], 16, 64);
        acc[j] += __shfl_xor(acc[j], 32, 64);
    }
    if (eg == 0) {
        const float nrm = rsqrtf(fmaxf((float)(s1 - s0), 1.0f));
        uint4 o;
        unsigned w[4];
#pragma unroll
        for (int m = 0; m < 4; ++m) {
            float e0 = acc[2 * m]     * nrm + b[cb + 2 * m];
            float e1 = acc[2 * m + 1] * nrm + b[cb + 2 * m + 1];
            w[m] = (unsigned)f2bf(e0) | ((unsigned)f2bf(e1) << 16);
        }
        o.x = w[0]; o.y = w[1]; o.z = w[2]; o.w = w[3];
        *reinterpret_cast<uint4*>(h2 + (size_t)node * D + cb) = o;
    }
}

// ---------------- Kernel 6: column sums / sumsq of bf16 h2 ----------------
__global__ __launch_bounds__(256) void k_stats(const unsigned* __restrict__ h2u,
                                               float* __restrict__ stats) {
    __shared__ float red[4][256];
    const int t = threadIdx.x;
    float s1lo = 0.f, s1hi = 0.f, s2lo = 0.f, s2hi = 0.f;
    const int total = NN * (D / 2);
    const int stride = gridDim.x * 256;
    for (int i = blockIdx.x * 256 + t; i < total; i += stride) {
        unsigned v = h2u[i];
        float lo = bflo(v), hi = bfhi(v);
        s1lo += lo; s1hi += hi;
        s2lo += lo * lo; s2hi += hi * hi;
    }
    red[0][t] = s1lo; red[1][t] = s1hi; red[2][t] = s2lo; red[3][t] = s2hi;
    __syncthreads();
    if (t < 64) {
        const int c = t * 2;
        float a0 = red[0][t] + red[0][t + 64] + red[0][t + 128] + red[0][t + 192];
        float a1 = red[1][t] + red[1][t + 64] + red[1][t + 128] + red[1][t + 192];
        float q0 = red[2][t] + red[2][t + 64] + red[2][t + 128] + red[2][t + 192];
        float q1 = red[3][t] + red[3][t + 64] + red[3][t + 128] + red[3][t + 192];
        atomicAdd(&stats[c], a0);
        atomicAdd(&stats[c + 1], a1);
        atomicAdd(&stats[128 + c], q0);
        atomicAdd(&stats[128 + c + 1], q1);
    }
}

// ---------------- Kernel 7: BN + ReLU + residual, 16B vectorized ----------------
__global__ void k_final(const uint2* __restrict__ h2v, const float4* __restrict__ xv,
                        const float* __restrict__ gamma, const float* __restrict__ beta,
                        const float* __restrict__ stats, float4* __restrict__ outv) {
    const int i = blockIdx.x * 256 + threadIdx.x;
    const int total = NN * (D / 4);
    if (i >= total) return;
    const int c = (i & 31) * 4;
    const float inv_n = 1.0f / (float)NN;
    uint2 v = h2v[i];
    float4 xx = xv[i];
    float hv[4] = { bflo(v.x), bfhi(v.x), bflo(v.y), bfhi(v.y) };
    float xr[4] = { xx.x, xx.y, xx.z, xx.w };
    float o[4];
#pragma unroll
    for (int m = 0; m < 4; ++m) {
        float mean = stats[c + m] * inv_n;
        float var  = stats[128 + c + m] * inv_n - mean * mean;
        float t = (hv[m] - mean) * rsqrtf(var + BN_EPS) * gamma[c + m] + beta[c + m];
        o[m] = fmaxf(t, 0.0f) + xr[m];
    }
    float4 ov; ov.x = o[0]; ov.y = o[1]; ov.z = o[2]; ov.w = o[3];
    outv[i] = ov;
}

extern "C" void kernel_launch(void* const* d_in, const int* in_sizes, int n_in,
                              void* d_out, int out_size, void* d_ws, size_t ws_size,
                              hipStream_t stream) {
    const float* x     = (const float*)d_in[0];
    const int*   src   = (const int*)d_in[1];
    const int*   dst   = (const int*)d_in[2];
    const float* W     = (const float*)d_in[3];
    const float* b     = (const float*)d_in[4];
    const float* gamma = (const float*)d_in[5];
    const float* beta  = (const float*)d_in[6];
    float* out = (float*)d_out;

    // Workspace layout (first NN*D floats reserved for h2/overlays)
    float* ws     = (float*)d_ws;
    ushort* h2    = (ushort*)ws;                      // NN*D bf16 (written by k_agg)
    float* degout = ws + (size_t)NN * D;              // NN
    float* stats  = degout + NN;                      // 256 (zeroed by k_front)
    int*   ptr    = (int*)(stats + 256);              // NN+1
    int*   esrc   = ptr + (NN + 1);                   // NE
    ushort* WT    = (ushort*)(esrc + NE);             // 128*128 bf16

    // Overlays in the h2 region (all dead before k_agg writes h2): ~38.8 MB < 51.2 MB
    int* sedge    = (int*)ws;                         // NE (packed src | (dst&127)<<17)
    int* SP       = sedge + NE;                       // NSLICE*SCH*SW = 31.5 MB
    int* P        = SP + (size_t)NSLICE * SCH * SW;   // CB*NC
    int* bintotal = P + (size_t)CB * NC;              // CB
    int* binbase  = bintotal + CB;                    // CB+1

    // h (bf16) lives in d_out (overwritten by k_final at the end)
    ushort* h = (ushort*)d_out;

    k_front<<<NSLICE * SCH, 256, 0, stream>>>(src, dst, W, WT, SP, P, stats);
    k_mid<<<CB + SMB, 256, 0, stream>>>(P, bintotal, SP, degout);
    k_csg<<<GB + NC, 256, 0, stream>>>(x, degout, WT, h, dst, src, P, bintotal, binbase, sedge);
    k_fine<<<CB, 256, 0, stream>>>(sedge, binbase, ptr, esrc);
    k_agg<<<(NN + 3) / 4, 256, 0, stream>>>(h, ptr, esrc, b, h2);
    k_stats<<<1024, 256, 0, stream>>>((const unsigned*)h2, stats);
    k_final<<<(NN * (D / 4) + 255) / 256, 256, 0, stream>>>((const uint2*)h2, (const float4*)x,
                                                            gamma, beta, stats, (float4*)out);
}